// Round 2
// baseline (12833.434 us; speedup 1.0000x reference)
//
#include <hip/hip_runtime.h>
#include <hip/hip_fp16.h>

#define Bb 128
#define Tt 1024
#define Ii 256
#define Hh 512
#define Cc 10

#define HG   16          // column groups (32 cols each)
#define NBLK 64          // 16 hg x 4 bg
#define COLS 32          // output cols per block
#define ROWS 32          // batch rows per block
#define LDP  520         // padded fp16 leading dim for K=512 (1040B: conflict-free b128)
#define LDPI 264         // padded for K=256
#define FLAG_STRIDE 32   // u32s between block flags (128B)

typedef _Float16 f16;
typedef _Float16 f16x8 __attribute__((ext_vector_type(8)));
typedef _Float16 f16x4 __attribute__((ext_vector_type(4)));
typedef _Float16 f16x2 __attribute__((ext_vector_type(2)));
typedef float    f32x4 __attribute__((ext_vector_type(4)));

static __device__ __forceinline__ f32x4 mfma16(f16x8 a, f16x8 b, f32x4 c) {
  return __builtin_amdgcn_mfma_f32_16x16x32_f16(a, b, c, 0, 0, 0);
}

static __device__ __forceinline__ float fast_tanh(float v) {
  float e = __expf(2.0f * v);
  return 1.0f - 2.0f / (e + 1.0f);
}

// 16B fragment load from coherent (IC) path: two 8B relaxed agent atomics (sc1)
static __device__ __forceinline__ f16x8 ld_h16(const f16* p) {
  union { unsigned long long u[2]; f16x8 v; } U;
  U.u[0] = __hip_atomic_load((const unsigned long long*)p,     __ATOMIC_RELAXED, __HIP_MEMORY_SCOPE_AGENT);
  U.u[1] = __hip_atomic_load((const unsigned long long*)p + 1, __ATOMIC_RELAXED, __HIP_MEMORY_SCOPE_AGENT);
  return U.v;
}

static __device__ __forceinline__ void st_u32(unsigned* p, unsigned v) {
  __hip_atomic_store(p, v, __ATOMIC_RELAXED, __HIP_MEMORY_SCOPE_AGENT);
}

__global__ __launch_bounds__(256, 1) void rnn_persistent(
    const float* __restrict__ x,
    const float* __restrict__ w_ih1, const float* __restrict__ w_hh1,
    const float* __restrict__ b_ih1, const float* __restrict__ b_hh1,
    const float* __restrict__ w_ih2, const float* __restrict__ w_hh2,
    const float* __restrict__ b_ih2, const float* __restrict__ b_hh2,
    const float* __restrict__ w_out, const float* __restrict__ b_out,
    float* __restrict__ out,
    unsigned* __restrict__ flags,    // NBLK flags, FLAG_STRIDE u32 apart
    f16* __restrict__ h1base,        // 2 x [128][512] fp16 ping-pong
    f16* __restrict__ h2base)        // 2 x [128][512] fp16 ping-pong
{
  __shared__ __align__(16) f16 ls_whh1[COLS][LDP];
  __shared__ __align__(16) f16 ls_wih2[COLS][LDP];
  __shared__ __align__(16) f16 ls_whh2[COLS][LDP];
  __shared__ __align__(16) f16 ls_wih1[COLS][LDPI];
  __shared__ float ls_b1[COLS], ls_b2[COLS];

  const int hg   = blockIdx.x & (HG - 1);
  const int bg   = blockIdx.x >> 4;
  const int col0 = hg * COLS;
  const int row0 = bg * ROWS;

  // ---- one-time weight staging: fp32 global -> fp16 LDS (padded) ----
  for (int v = threadIdx.x; v < COLS * (Hh / 4); v += 256) {
    const int j  = v >> 7;
    const int k4 = v & 127;
    const int gj = col0 + j;
    float4 a;
    a = ((const float4*)w_hh1)[gj * (Hh / 4) + k4];
    { f16x4 h = { (f16)a.x, (f16)a.y, (f16)a.z, (f16)a.w };
      *(f16x4*)&ls_whh1[j][k4 * 4] = h; }
    a = ((const float4*)w_ih2)[gj * (Hh / 4) + k4];
    { f16x4 h = { (f16)a.x, (f16)a.y, (f16)a.z, (f16)a.w };
      *(f16x4*)&ls_wih2[j][k4 * 4] = h; }
    a = ((const float4*)w_hh2)[gj * (Hh / 4) + k4];
    { f16x4 h = { (f16)a.x, (f16)a.y, (f16)a.z, (f16)a.w };
      *(f16x4*)&ls_whh2[j][k4 * 4] = h; }
  }
  for (int v = threadIdx.x; v < COLS * (Ii / 4); v += 256) {
    const int j  = v >> 6;
    const int k4 = v & 63;
    float4 a = ((const float4*)w_ih1)[(col0 + j) * (Ii / 4) + k4];
    f16x4 h = { (f16)a.x, (f16)a.y, (f16)a.z, (f16)a.w };
    *(f16x4*)&ls_wih1[j][k4 * 4] = h;
  }
  if (threadIdx.x < COLS) {
    ls_b1[threadIdx.x] = b_ih1[col0 + threadIdx.x] + b_hh1[col0 + threadIdx.x];
    ls_b2[threadIdx.x] = b_ih2[col0 + threadIdx.x] + b_hh2[col0 + threadIdx.x];
  }
  __syncthreads();

  // ---- per-thread fragment geometry (16x16x32 MFMA) ----
  const int wid  = threadIdx.x >> 6;
  const int lane = threadIdx.x & 63;
  const int wr   = wid >> 1;
  const int wc   = wid & 1;
  const int lm   = lane & 15;
  const int lk8  = (lane >> 4) * 8;
  const int arow = row0 + wr * 16 + lm;
  const int lcol = wc * 16 + lm;
  const float bias1 = ls_b1[lcol];
  const float bias2 = ls_b2[lcol];
  const int drow0 = row0 + wr * 16 + (lane >> 4) * 4;
  const int dcol  = col0 + lcol;
  const int ce2   = dcol >> 1;             // u32 column index (paired cols)
  const int rlo   = (lane & 1) * 2;        // this lane stores rows rlo, rlo+1
  const size_t HB = (size_t)Bb * Hh;
  unsigned* const myflag = flags + (unsigned)blockIdx.x * FLAG_STRIDE;

  // x-part of phase 0 (no h dependency)
  f32x4 xacc = {0.f, 0.f, 0.f, 0.f};
  {
    const float* xr = x + (size_t)arow * (Tt * (size_t)Ii) + lk8;
    #pragma unroll
    for (int kc = 0; kc < Ii / 32; ++kc) {
      float4 xa = *(const float4*)(xr + kc * 32);
      float4 xb = *(const float4*)(xr + kc * 32 + 4);
      f16x8 a = { (f16)xa.x, (f16)xa.y, (f16)xa.z, (f16)xa.w,
                  (f16)xb.x, (f16)xb.y, (f16)xb.z, (f16)xb.w };
      xacc = mfma16(a, *(const f16x8*)&ls_wih1[lcol][kc * 32 + lk8], xacc);
    }
  }

  // ---- pipelined recurrence: phase p computes h1_p and h2_{p-1} ----
  for (int p = 0; p <= Tt; ++p) {
    const int cur = p & 1;
    const size_t curo = (size_t)cur * HB;
    const size_t prvo = (size_t)(cur ^ 1) * HB;
    const bool do1 = (p < Tt);
    const bool do2 = (p > 0);

    f32x4 acc1 = do1 ? xacc : f32x4{0.f, 0.f, 0.f, 0.f};
    f32x4 acc2 = {0.f, 0.f, 0.f, 0.f};

    if (do2) {
      // h1_{p-1} feeds BOTH w_hh1 (acc1) and w_ih2 (acc2): shared A-frags
      const f16* hr1 = h1base + prvo + (size_t)arow * Hh + lk8;
      #pragma unroll
      for (int kc = 0; kc < Hh / 32; ++kc) {
        f16x8 a = ld_h16(hr1 + kc * 32);
        if (do1) acc1 = mfma16(a, *(const f16x8*)&ls_whh1[lcol][kc * 32 + lk8], acc1);
        acc2 = mfma16(a, *(const f16x8*)&ls_wih2[lcol][kc * 32 + lk8], acc2);
      }
      // h2_{p-2} @ w_hh2^T
      const f16* hr2 = h2base + curo + (size_t)arow * Hh + lk8;
      #pragma unroll
      for (int kc = 0; kc < Hh / 32; ++kc) {
        f16x8 a = ld_h16(hr2 + kc * 32);
        acc2 = mfma16(a, *(const f16x8*)&ls_whh2[lcol][kc * 32 + lk8], acc2);
      }
    }

    // ---- tanh + pack pairs of cols into u32, sc1 store ----
    if (do1) {
      float v0 = fast_tanh(acc1[0] + bias1);
      float v1 = fast_tanh(acc1[1] + bias1);
      float v2 = fast_tanh(acc1[2] + bias1);
      float v3 = fast_tanh(acc1[3] + bias1);
      float o0 = __shfl_xor(v0, 1, 64), o1 = __shfl_xor(v1, 1, 64);
      float o2 = __shfl_xor(v2, 1, 64), o3 = __shfl_xor(v3, 1, 64);
      float m[4] = {v0, v1, v2, v3}, q[4] = {o0, o1, o2, o3};
      unsigned* b32 = (unsigned*)(h1base + curo);
      #pragma unroll
      for (int r = 0; r < 2; ++r) {
        int rr = rlo + r;
        float ve = (lane & 1) ? q[rr] : m[rr];
        float vo = (lane & 1) ? m[rr] : q[rr];
        union { f16x2 h; unsigned u; } P; P.h = f16x2{(f16)ve, (f16)vo};
        st_u32(b32 + (size_t)(drow0 + rr) * (Hh / 2) + ce2, P.u);
      }
    }
    if (do2) {
      float v0 = fast_tanh(acc2[0] + bias2);
      float v1 = fast_tanh(acc2[1] + bias2);
      float v2 = fast_tanh(acc2[2] + bias2);
      float v3 = fast_tanh(acc2[3] + bias2);
      float o0 = __shfl_xor(v0, 1, 64), o1 = __shfl_xor(v1, 1, 64);
      float o2 = __shfl_xor(v2, 1, 64), o3 = __shfl_xor(v3, 1, 64);
      float m[4] = {v0, v1, v2, v3}, q[4] = {o0, o1, o2, o3};
      unsigned* b32 = (unsigned*)(h2base + prvo);
      #pragma unroll
      for (int r = 0; r < 2; ++r) {
        int rr = rlo + r;
        float ve = (lane & 1) ? q[rr] : m[rr];
        float vo = (lane & 1) ? m[rr] : q[rr];
        union { f16x2 h; unsigned u; } P; P.h = f16x2{(f16)ve, (f16)vo};
        st_u32(b32 + (size_t)(drow0 + rr) * (Hh / 2) + ce2, P.u);
      }
    }

    // ---- distributed barrier: release own flag, overlap x-GEMM, poll all ----
    __syncthreads();                  // drains vmcnt(0): all block's h stores acked at IC
    const unsigned tgt = (unsigned)(p + 1);
    if (threadIdx.x == 0) st_u32(myflag, tgt);

    if (p + 1 < Tt) {
      // x-part of phase p+1, hidden under the barrier wait
      f32x4 xa_ = {0.f, 0.f, 0.f, 0.f};
      const float* xr = x + (size_t)arow * (Tt * (size_t)Ii) + (size_t)(p + 1) * Ii + lk8;
      #pragma unroll
      for (int kc = 0; kc < Ii / 32; ++kc) {
        float4 xa = *(const float4*)(xr + kc * 32);
        float4 xb = *(const float4*)(xr + kc * 32 + 4);
        f16x8 a = { (f16)xa.x, (f16)xa.y, (f16)xa.z, (f16)xa.w,
                    (f16)xb.x, (f16)xb.y, (f16)xb.z, (f16)xb.w };
        xa_ = mfma16(a, *(const f16x8*)&ls_wih1[lcol][kc * 32 + lk8], xa_);
      }
      xacc = xa_;
    }

    if (wid == 0) {
      unsigned v;
      do {
        v = __hip_atomic_load(flags + lane * FLAG_STRIDE, __ATOMIC_RELAXED, __HIP_MEMORY_SCOPE_AGENT);
      } while (!__all((int)(v >= tgt)));
    }
    __syncthreads();
  }

  // ---- final: out = h2_{T-1} @ w_out^T + b_out (h2 final is in buffer 1) ----
  if (wid < 2) {
    const int row = blockIdx.x * 2 + wid;
    const f16* hr = h2base + HB + (size_t)row * Hh + lane * 8;
    union { unsigned long long u[2]; f16 h[8]; } U;
    U.u[0] = __hip_atomic_load((const unsigned long long*)hr,     __ATOMIC_RELAXED, __HIP_MEMORY_SCOPE_AGENT);
    U.u[1] = __hip_atomic_load((const unsigned long long*)hr + 1, __ATOMIC_RELAXED, __HIP_MEMORY_SCOPE_AGENT);
    float hf[8];
    #pragma unroll
    for (int j = 0; j < 8; ++j) hf[j] = (float)U.h[j];
    #pragma unroll
    for (int c = 0; c < Cc; ++c) {
      const float* wr_ = w_out + (size_t)c * Hh + lane * 8;
      float4 wa = *(const float4*)wr_;
      float4 wb = *(const float4*)(wr_ + 4);
      float s = hf[0]*wa.x + hf[1]*wa.y + hf[2]*wa.z + hf[3]*wa.w
              + hf[4]*wb.x + hf[5]*wb.y + hf[6]*wb.z + hf[7]*wb.w;
      #pragma unroll
      for (int off = 32; off >= 1; off >>= 1) s += __shfl_down(s, off, 64);
      if (lane == 0) out[row * Cc + c] = s + b_out[c];
    }
  }
}

extern "C" void kernel_launch(void* const* d_in, const int* in_sizes, int n_in,
                              void* d_out, int out_size, void* d_ws, size_t ws_size,
                              hipStream_t stream) {
  (void)in_sizes; (void)n_in; (void)out_size; (void)ws_size;
  const float* x     = (const float*)d_in[0];
  const float* w_ih1 = (const float*)d_in[1];
  const float* w_hh1 = (const float*)d_in[2];
  const float* b_ih1 = (const float*)d_in[3];
  const float* b_hh1 = (const float*)d_in[4];
  const float* w_ih2 = (const float*)d_in[5];
  const float* w_hh2 = (const float*)d_in[6];
  const float* b_ih2 = (const float*)d_in[7];
  const float* b_hh2 = (const float*)d_in[8];
  const float* w_out = (const float*)d_in[9];
  const float* b_out = (const float*)d_in[10];
  float* out = (float*)d_out;

  unsigned* flags = (unsigned*)d_ws;                 // 64 * 128B = 8KB
  _Float16* h1base = (_Float16*)((char*)d_ws + 8192);
  _Float16* h2base = h1base + 2 * (size_t)Bb * Hh;

  // zero flags + both ping-pong state buffers (h_{-1} = 0)
  const size_t clear_bytes = 8192 + 4 * (size_t)Bb * Hh * sizeof(_Float16);
  hipMemsetAsync(d_ws, 0, clear_bytes, stream);

  hipLaunchKernelGGL(rnn_persistent, dim3(NBLK), dim3(256), 0, stream,
                     x, w_ih1, w_hh1, b_ih1, b_hh1,
                     w_ih2, w_hh2, b_ih2, b_hh2, w_out, b_out,
                     out, flags, h1base, h2base);
}